// Round 14
// baseline (74.956 us; speedup 1.0000x reference)
//
#include <hip/hip_runtime.h>
#include <math.h>

#define BSZ 4
#define NN  256
#define CC  96
#define TT  16                 // tile side
#define NTILES 136             // 16*17/2 triangular tiles per batch
#define RSTR 100               // LDS row stride (floats): 16B-aligned, 2-way banks free
#define ARR  (TT * RSTR)       // 1600 floats per array

#define XIN_OFF  0
#define EH_OFF   2048          // BSZ*NN*2
#define COV_OFF  100352        // 2048 + BSZ*NN*CC

#define INV_SQRT_2PI 0.3989422804014327f
#define EXP2C       -0.7213475204444817f   // -0.5*log2(e)
// Row/Eh phases: Abramowitz-Stegun 7.1.25 (3-term), Phi abs err ~1.3e-5.
#define PHI_P   0.33267253f
#define PHI_C1  0.1740121f
#define PHI_C2 -0.0479399f
#define PHI_C3  0.3739278f
// Pair phase Phi: clamped odd cubic-in-s fit of (Phi(u)-0.5)/u, s=u^2 (R11).
#define PA0  0.39712f
#define PA1 -0.060411f
#define PA2  0.0061591f
#define PA3 -0.00025640f
// Pair phase pdf: quartic Chebyshev fit of exp(-s/2), s=u^2 in [0,9] (R13).
#define PB0  0.99521f
#define PB1 -0.471073f
#define PB2  0.0955511f
#define PB3 -0.00930823f
#define PB4  0.000351287f

typedef float v2f __attribute__((ext_vector_type(2)));

__device__ __forceinline__ v2f v2s(float s) { v2f r; r.x = s; r.y = s; return r; }

#if __has_builtin(__builtin_elementwise_fma)
#define V2FMA(a, b, c) __builtin_elementwise_fma((v2f)(a), (v2f)(b), (v2f)(c))
#else
#define V2FMA(a, b, c) ((a) * (b) + (c))
#endif

#if __has_builtin(__builtin_elementwise_min) && __has_builtin(__builtin_elementwise_max)
__device__ __forceinline__ v2f v2_clamp3(v2f u) {
    return __builtin_elementwise_max(__builtin_elementwise_min(u, v2s(3.0f)), v2s(-3.0f));
}
#else
__device__ __forceinline__ v2f v2_clamp3(v2f u) {
    v2f r;
    r.x = fminf(fmaxf(u.x, -3.0f), 3.0f);
    r.y = fminf(fmaxf(u.y, -3.0f), 3.0f);
    return r;
}
#endif

__device__ __forceinline__ float phi_from_exp_s(float u, float e) {
    float t  = __builtin_amdgcn_rcpf(__builtin_fmaf(PHI_P, fabsf(u), 1.0f));
    float hp = __builtin_fmaf(__builtin_fmaf(PHI_C3, t, PHI_C2), t, PHI_C1) * t * e;
    return 0.5f + __builtin_copysignf(0.5f - hp, u);
}

__device__ __forceinline__ int tri_offset(int k) {   // tiles before row k
    return k * TT - (k * (k - 1)) / 2;
}
__device__ __forceinline__ void tri_decode(int t, int& ti, int& tj) {
    float disc = 1089.0f - 8.0f * (float)t;          // (2T+1)^2 - 8t, T=16
    ti = (int)((33.0f - __builtin_amdgcn_sqrtf(disc)) * 0.5f);
    while (tri_offset(ti + 1) <= t) ++ti;            // float-precision fixup
    while (tri_offset(ti) > t) --ti;
    tj = ti + (t - tri_offset(ti));
}

// Single fused kernel. R13 math; per-pair setup HOISTED before the Eh phase
// so its scattered kin loads + sqrt/rcp chains hide under Phase-2 compute.
__global__ __launch_bounds__(512) void relu_cov_fused(
    const float* __restrict__ xin, const float* __restrict__ meanin,
    const float* __restrict__ kin, float* __restrict__ out)
{
    const int blk = blockIdx.x;     // b*NTILES + t
    const int b   = blk / NTILES;
    const int t   = blk - b * NTILES;
    const int tid = threadIdx.x;

    int ti, tj;
    tri_decode(t, ti, tj);
    const bool diag = (ti == tj);

    __shared__ __align__(16) float lds[4 * ARR];   // [smi | sEi | smj | sEj]
    __shared__ float red[8 * 256];                 // [chunk][pair]
    __shared__ float srowS[32], srowR[32], srowV[32];
    float* const smi = lds;
    float* const sEi = lds + ARR;
    float* const smj = lds + 2 * ARR;
    float* const sEj = lds + 3 * ARR;

    // --- Phase 1: row consts + stage meanin ---
    if (tid < 32) {
        int row = (tid < 16) ? (ti * TT + tid) : (tj * TT + (tid - 16));
        float kd  = kin[((size_t)(b * NN + row)) * NN + row] + 1e-6f;
        float var = fmaxf(kd, 1e-8f);
        float st  = __builtin_amdgcn_sqrtf(var);
        srowV[tid] = var;
        srowS[tid] = st;
        srowR[tid] = __builtin_amdgcn_rcpf(st);
    }
#pragma unroll
    for (int it = 0; it < 2; ++it) {
        int k = tid + it * 512;         // 2 arrays x 16 rows x 24 float4 = 768
        if (k < 768) {
            int arr = k / 384;          // 0 = i-rows, 1 = j-rows
            int rem = k - arr * 384;
            int r   = rem / 24;
            int q   = rem - r * 24;
            int row = ((arr == 0) ? ti : tj) * TT + r;
            float4 v = *((const float4*)(meanin + ((size_t)(b * NN + row)) * CC) + q);
            *(float4*)(lds + arr * 2 * ARR + r * RSTR + q * 4) = v;
        }
    }
    __syncthreads();

    // --- HOISTED per-pair setup (depends only on kin + srowV) ---
    const int pt = tid & 63;        // pair-thread
    const int ch = tid >> 6;        // c-chunk 0..7 (12 c each)
    const int ia = (pt >> 3) * 2;   // i_loc base (0,2,..,14)
    const int jb = (pt & 7) * 2;    // j_loc base
    const int c0 = ch * 12;

    float Ci00[2][2], Ci01[2][2], Ci11[2][2], Cm01[2][2];
    float Cqd[2][2], Cqj[2][2], Cqi[2][2], Cc2[2][2];
    {
        const float* kb = kin + (size_t)b * NN * NN;
        float2 k2r[2];
#pragma unroll
        for (int ii = 0; ii < 2; ++ii)   // issue both scattered loads first
            k2r[ii] = *(const float2*)(kb + (size_t)(ti * TT + ia + ii) * NN + tj * TT + jb);
#pragma unroll
        for (int ii = 0; ii < 2; ++ii) {
            const float m00 = srowV[ia + ii];
#pragma unroll
            for (int jj = 0; jj < 2; ++jj) {
                const float m11 = srowV[16 + jb + jj];
                const float m01 = (jj == 0) ? k2r[ii].x : k2r[ii].y;
                const float det = __builtin_fmaf(-m01, m01, m00 * m11);
                const float s   = __builtin_amdgcn_sqrtf(fmaxf(det, 1e-8f));
                const float tt  = fmaxf(__builtin_amdgcn_sqrtf(m00 + m11 + 2.0f * s), 1e-8f);
                const float rt  = __builtin_amdgcn_rcpf(tt);
                const float s00 = (m00 + s) * rt;
                const float s01 = m01 * rt;
                const float s11 = (m11 + s) * rt;
                const float dS  = fmaxf(__builtin_fmaf(-s01, s01, s00 * s11), 1e-8f);
                const float rdS = __builtin_amdgcn_rcpf(dS);
                Ci00[ii][jj] = s11 * rdS;
                Ci01[ii][jj] = -s01 * rdS;
                Ci11[ii][jj] = s00 * rdS;
                Cm01[ii][jj] = m01;
                Cqd[ii][jj]  = -INV_SQRT_2PI * s01 * s01 * s01 * rdS;
                Cqj[ii][jj]  =  INV_SQRT_2PI * s00 * s00 * s11 * rdS;
                Cqi[ii][jj]  =  INV_SQRT_2PI * s00 * s11 * s11 * rdS;
                Cc2[ii][jj]  = 2.0f * INV_SQRT_2PI * INV_SQRT_2PI * s01 * s01;
            }
        }
    }

    // --- Phase 2: Eh for 32 rows (overlaps the setup's latency) ---
#pragma unroll
    for (int it = 0; it < 6; ++it) {
        int k   = tid + it * 512;
        int arr = k / 1536;
        int rem = k - arr * 1536;
        int r   = rem / 96;
        int c   = rem - r * 96;
        float m  = lds[arr * 2 * ARR + r * RSTR + c];
        float st = srowS[arr * 16 + r];
        float rs = srowR[arr * 16 + r];
        float z  = m * rs;
        float e  = __builtin_amdgcn_exp2f(z * z * EXP2C);
        float Ph = phi_from_exp_s(z, e);
        float Eh = __builtin_fmaf(m, Ph, st * (INV_SQRT_2PI * e));
        lds[(arr * 2 + 1) * ARR + r * RSTR + c] = Eh;
    }
    __syncthreads();

    // --- Phase 2b: diagonal-tile global outputs ---
    if (diag) {
#pragma unroll
        for (int it = 0; it < 3; ++it) {         // Eh output: 16 x 96
            int k = tid + it * 512;
            int r = k / 96, c = k - r * 96;
            out[EH_OFF + ((size_t)(b * NN + ti * TT + r)) * CC + c] = sEi[r * RSTR + c];
        }
        if (tid < 32) {                          // xin copy: 16 rows x 2
            int r = tid >> 1, d = tid & 1;
            size_t o = ((size_t)(b * NN + ti * TT + r)) * 2 + d;
            out[XIN_OFF + o] = xin[o];
        }
        {                                        // dvals: tid = r*32 + s, 3 c each
            int r = tid >> 5, s = tid & 31;
            float st = srowS[r], var = srowV[r], rs = srowR[r];
            float dsum = 0.0f;
#pragma unroll
            for (int dc = 0; dc < 3; ++dc) {
                int c = s * 3 + dc;
                float m  = smi[r * RSTR + c];
                float Eh = sEi[r * RSTR + c];
                float z  = m * rs;
                float e  = __builtin_amdgcn_exp2f(z * z * EXP2C);
                float Ph = phi_from_exp_s(z, e);
                float ph = INV_SQRT_2PI * e;
                float dt = __builtin_fmaf(__builtin_fmaf(m, m, var), Ph,
                           __builtin_fmaf(m * st, ph, -Eh * Eh));
                dsum += dt;
            }
            dsum += __shfl_down(dsum, 16, 32);
            dsum += __shfl_down(dsum,  8, 32);
            dsum += __shfl_down(dsum,  4, 32);
            dsum += __shfl_down(dsum,  2, 32);
            dsum += __shfl_down(dsum,  1, 32);
            if (s == 0) {
                float dval = fmaxf(dsum * (1.0f / 96.0f), 1e-6f);
                int row = ti * TT + r;
                out[COV_OFF + ((size_t)(b * NN + row)) * NN + row] = dval + 1e-6f;
            }
        }
    }

    // --- Phase 3: inner loop (packed, trans-free, packed clamps) ---
    v2f acc[2][2] = {{v2s(0.0f), v2s(0.0f)}, {v2s(0.0f), v2s(0.0f)}};

    auto elem2 = [&](int ii, int jj, v2f mi, v2f mj, v2f Ei, v2f Ej) {
        v2f u1 = V2FMA(v2s(Ci01[ii][jj]), mj, v2s(Ci00[ii][jj]) * mi);
        v2f u2 = V2FMA(v2s(Ci11[ii][jj]), mj, v2s(Ci01[ii][jj]) * mi);
        v2f uc1 = v2_clamp3(u1);
        v2f uc2 = v2_clamp3(u2);
        v2f s1 = uc1 * uc1;
        v2f s2 = uc2 * uc2;
        v2f P1 = V2FMA(V2FMA(V2FMA(v2s(PA3), s1, v2s(PA2)), s1, v2s(PA1)), s1, v2s(PA0));
        v2f P2 = V2FMA(V2FMA(V2FMA(v2s(PA3), s2, v2s(PA2)), s2, v2s(PA1)), s2, v2s(PA0));
        v2f Phi1 = V2FMA(uc1, P1, v2s(0.5f));
        v2f Phi2 = V2FMA(uc2, P2, v2s(0.5f));
        v2f e1 = V2FMA(V2FMA(V2FMA(V2FMA(v2s(PB4), s1, v2s(PB3)), s1, v2s(PB2)),
                             s1, v2s(PB1)), s1, v2s(PB0));
        v2f e2 = V2FMA(V2FMA(V2FMA(V2FMA(v2s(PB4), s2, v2s(PB3)), s2, v2s(PB2)),
                             s2, v2s(PB1)), s2, v2s(PB0));
        v2f a  = V2FMA(mi, mj, v2s(Cm01[ii][jj]));
        v2f bb = V2FMA(v2s(Cqd[ii][jj]), mi, v2s(Cqj[ii][jj]) * mj);
        v2f cc = V2FMA(v2s(Cqi[ii][jj]), mi, v2s(Cqd[ii][jj]) * mj);
        v2f ta = V2FMA(a,  Phi1, bb * e1);
        v2f tb = V2FMA(cc, Phi1, v2s(Cc2[ii][jj]) * e1);
        v2f A  = acc[ii][jj];
        A = V2FMA(Phi2, ta, A);
        A = V2FMA(e2,   tb, A);
        A = V2FMA(-Ei,  Ej, A);
        acc[ii][jj] = A;
    };

#pragma unroll
    for (int q = 0; q < 3; ++q) {
        const int co = c0 + q * 4;
        float4 mi4[2], Ei4[2], mj4[2], Ej4[2];
#pragma unroll
        for (int r = 0; r < 2; ++r) {
            mi4[r] = *(const float4*)(smi + (ia + r) * RSTR + co);
            Ei4[r] = *(const float4*)(sEi + (ia + r) * RSTR + co);
            mj4[r] = *(const float4*)(smj + (jb + r) * RSTR + co);
            Ej4[r] = *(const float4*)(sEj + (jb + r) * RSTR + co);
        }
#pragma unroll
        for (int ii = 0; ii < 2; ++ii) {
#pragma unroll
            for (int jj = 0; jj < 2; ++jj) {
                v2f miL = {mi4[ii].x, mi4[ii].y}, miH = {mi4[ii].z, mi4[ii].w};
                v2f mjL = {mj4[jj].x, mj4[jj].y}, mjH = {mj4[jj].z, mj4[jj].w};
                v2f EiL = {Ei4[ii].x, Ei4[ii].y}, EiH = {Ei4[ii].z, Ei4[ii].w};
                v2f EjL = {Ej4[jj].x, Ej4[jj].y}, EjH = {Ej4[jj].z, Ej4[jj].w};
                elem2(ii, jj, miL, mjL, EiL, EjL);
                elem2(ii, jj, miH, mjH, EiH, EjH);
            }
        }
    }

#pragma unroll
    for (int ii = 0; ii < 2; ++ii)
#pragma unroll
        for (int jj = 0; jj < 2; ++jj)
            red[ch * 256 + (ia + ii) * 16 + (jb + jj)] =
                acc[ii][jj].x + acc[ii][jj].y;
    __syncthreads();

    if (tid < 256) {
        float sum = 0.0f;
#pragma unroll
        for (int k = 0; k < 8; ++k) sum += red[k * 256 + tid];
        const int i = ti * TT + (tid >> 4);
        const int j = tj * TT + (tid & 15);
        if (i < j) {
            float v = sum * (1.0f / 96.0f);
            out[COV_OFF + ((size_t)(b * NN + i)) * NN + j] = v;
            out[COV_OFF + ((size_t)(b * NN + j)) * NN + i] = v;
        }
    }
}

extern "C" void kernel_launch(void* const* d_in, const int* in_sizes, int n_in,
                              void* d_out, int out_size, void* d_ws, size_t ws_size,
                              hipStream_t stream) {
    const float* xin    = (const float*)d_in[0];
    const float* meanin = (const float*)d_in[1];
    const float* kin    = (const float*)d_in[2];
    float* out = (float*)d_out;

    relu_cov_fused<<<BSZ * NTILES, 512, 0, stream>>>(xin, meanin, kin, out);
}

// Round 15
// 74.282 us; speedup vs baseline: 1.0091x; 1.0091x over previous
//
#include <hip/hip_runtime.h>
#include <math.h>

#define BSZ 4
#define NN  256
#define CC  96
#define TT  16                 // tile side
#define NTILES 136             // 16*17/2 triangular tiles per batch
#define RSTR 100               // LDS row stride (floats): 16B-aligned, 2-way banks free
#define ARR  (TT * RSTR)       // 1600 floats per array

#define XIN_OFF  0
#define EH_OFF   2048          // BSZ*NN*2
#define COV_OFF  100352        // 2048 + BSZ*NN*CC

#define INV_SQRT_2PI 0.3989422804014327f
#define EXP2C       -0.7213475204444817f   // -0.5*log2(e)
// Row/Eh phases: Abramowitz-Stegun 7.1.25 (3-term), Phi abs err ~1.3e-5.
#define PHI_P   0.33267253f
#define PHI_C1  0.1740121f
#define PHI_C2 -0.0479399f
#define PHI_C3  0.3739278f
// Pair phase Phi: clamped odd cubic-in-s fit of (Phi(u)-0.5)/u, s=u^2 (R11).
#define PA0  0.39712f
#define PA1 -0.060411f
#define PA2  0.0061591f
#define PA3 -0.00025640f
// Pair phase pdf: quartic Chebyshev fit of exp(-s/2), s=u^2 in [0,9] (R13).
#define PB0  0.99521f
#define PB1 -0.471073f
#define PB2  0.0955511f
#define PB3 -0.00930823f
#define PB4  0.000351287f

typedef float v2f __attribute__((ext_vector_type(2)));

__device__ __forceinline__ v2f v2s(float s) { v2f r; r.x = s; r.y = s; return r; }

#if __has_builtin(__builtin_elementwise_fma)
#define V2FMA(a, b, c) __builtin_elementwise_fma((v2f)(a), (v2f)(b), (v2f)(c))
#else
#define V2FMA(a, b, c) ((a) * (b) + (c))
#endif

#if __has_builtin(__builtin_elementwise_min) && __has_builtin(__builtin_elementwise_max)
__device__ __forceinline__ v2f v2_clamp3(v2f u) {
    return __builtin_elementwise_max(__builtin_elementwise_min(u, v2s(3.0f)), v2s(-3.0f));
}
#else
__device__ __forceinline__ v2f v2_clamp3(v2f u) {
    v2f r;
    r.x = fminf(fmaxf(u.x, -3.0f), 3.0f);
    r.y = fminf(fmaxf(u.y, -3.0f), 3.0f);
    return r;
}
#endif

__device__ __forceinline__ float phi_from_exp_s(float u, float e) {
    float t  = __builtin_amdgcn_rcpf(__builtin_fmaf(PHI_P, fabsf(u), 1.0f));
    float hp = __builtin_fmaf(__builtin_fmaf(PHI_C3, t, PHI_C2), t, PHI_C1) * t * e;
    return 0.5f + __builtin_copysignf(0.5f - hp, u);
}

__device__ __forceinline__ int tri_offset(int k) {   // tiles before row k
    return k * TT - (k * (k - 1)) / 2;
}
__device__ __forceinline__ void tri_decode(int t, int& ti, int& tj) {
    float disc = 1089.0f - 8.0f * (float)t;          // (2T+1)^2 - 8t, T=16
    ti = (int)((33.0f - __builtin_amdgcn_sqrtf(disc)) * 0.5f);
    while (tri_offset(ti + 1) <= t) ++ti;            // float-precision fixup
    while (tri_offset(ti) > t) --ti;
    tj = ti + (t - tri_offset(ti));
}

// Single fused kernel (R13 structure — best measured). Pair phase: 2x2 pair
// sub-tile per thread, c packed in pairs (VOP3P), Phi AND pdf clamped
// polynomials, packed pk_min/max clamps — zero transcendentals, zero scalar
// ops in the inner loop. Setup stays AFTER Phase 2b (R14's hoist regressed:
// +32 live VGPRs across Phase 2 cost more than the latency it hid).
__global__ __launch_bounds__(512) void relu_cov_fused(
    const float* __restrict__ xin, const float* __restrict__ meanin,
    const float* __restrict__ kin, float* __restrict__ out)
{
    const int blk = blockIdx.x;     // b*NTILES + t
    const int b   = blk / NTILES;
    const int t   = blk - b * NTILES;
    const int tid = threadIdx.x;

    int ti, tj;
    tri_decode(t, ti, tj);
    const bool diag = (ti == tj);

    __shared__ __align__(16) float lds[4 * ARR];   // [smi | sEi | smj | sEj]
    __shared__ float red[8 * 256];                 // [chunk][pair]
    __shared__ float srowS[32], srowR[32], srowV[32];
    float* const smi = lds;
    float* const sEi = lds + ARR;
    float* const smj = lds + 2 * ARR;
    float* const sEj = lds + 3 * ARR;

    // --- Phase 1: row consts + stage meanin ---
    if (tid < 32) {
        int row = (tid < 16) ? (ti * TT + tid) : (tj * TT + (tid - 16));
        float kd  = kin[((size_t)(b * NN + row)) * NN + row] + 1e-6f;
        float var = fmaxf(kd, 1e-8f);
        float st  = __builtin_amdgcn_sqrtf(var);
        srowV[tid] = var;
        srowS[tid] = st;
        srowR[tid] = __builtin_amdgcn_rcpf(st);
    }
#pragma unroll
    for (int it = 0; it < 2; ++it) {
        int k = tid + it * 512;         // 2 arrays x 16 rows x 24 float4 = 768
        if (k < 768) {
            int arr = k / 384;          // 0 = i-rows, 1 = j-rows
            int rem = k - arr * 384;
            int r   = rem / 24;
            int q   = rem - r * 24;
            int row = ((arr == 0) ? ti : tj) * TT + r;
            float4 v = *((const float4*)(meanin + ((size_t)(b * NN + row)) * CC) + q);
            *(float4*)(lds + arr * 2 * ARR + r * RSTR + q * 4) = v;
        }
    }
    __syncthreads();

    // --- Phase 2: Eh for 32 rows (accurate A&S path; feeds Eh output) ---
#pragma unroll
    for (int it = 0; it < 6; ++it) {
        int k   = tid + it * 512;
        int arr = k / 1536;
        int rem = k - arr * 1536;
        int r   = rem / 96;
        int c   = rem - r * 96;
        float m  = lds[arr * 2 * ARR + r * RSTR + c];
        float st = srowS[arr * 16 + r];
        float rs = srowR[arr * 16 + r];
        float z  = m * rs;
        float e  = __builtin_amdgcn_exp2f(z * z * EXP2C);
        float Ph = phi_from_exp_s(z, e);
        float Eh = __builtin_fmaf(m, Ph, st * (INV_SQRT_2PI * e));
        lds[(arr * 2 + 1) * ARR + r * RSTR + c] = Eh;
    }
    __syncthreads();

    // --- Phase 2b: diagonal-tile global outputs ---
    if (diag) {
#pragma unroll
        for (int it = 0; it < 3; ++it) {         // Eh output: 16 x 96
            int k = tid + it * 512;
            int r = k / 96, c = k - r * 96;
            out[EH_OFF + ((size_t)(b * NN + ti * TT + r)) * CC + c] = sEi[r * RSTR + c];
        }
        if (tid < 32) {                          // xin copy: 16 rows x 2
            int r = tid >> 1, d = tid & 1;
            size_t o = ((size_t)(b * NN + ti * TT + r)) * 2 + d;
            out[XIN_OFF + o] = xin[o];
        }
        {                                        // dvals: tid = r*32 + s, 3 c each
            int r = tid >> 5, s = tid & 31;
            float st = srowS[r], var = srowV[r], rs = srowR[r];
            float dsum = 0.0f;
#pragma unroll
            for (int dc = 0; dc < 3; ++dc) {
                int c = s * 3 + dc;
                float m  = smi[r * RSTR + c];
                float Eh = sEi[r * RSTR + c];
                float z  = m * rs;
                float e  = __builtin_amdgcn_exp2f(z * z * EXP2C);
                float Ph = phi_from_exp_s(z, e);
                float ph = INV_SQRT_2PI * e;
                float dt = __builtin_fmaf(__builtin_fmaf(m, m, var), Ph,
                           __builtin_fmaf(m * st, ph, -Eh * Eh));
                dsum += dt;
            }
            dsum += __shfl_down(dsum, 16, 32);
            dsum += __shfl_down(dsum,  8, 32);
            dsum += __shfl_down(dsum,  4, 32);
            dsum += __shfl_down(dsum,  2, 32);
            dsum += __shfl_down(dsum,  1, 32);
            if (s == 0) {
                float dval = fmaxf(dsum * (1.0f / 96.0f), 1e-6f);
                int row = ti * TT + r;
                out[COV_OFF + ((size_t)(b * NN + row)) * NN + row] = dval + 1e-6f;
            }
        }
    }

    // --- Phase 3: pair loop, 2x2 pairs per thread, packed, trans-free ---
    const int pt = tid & 63;        // pair-thread
    const int ch = tid >> 6;        // c-chunk 0..7 (12 c each)
    const int ia = (pt >> 3) * 2;   // i_loc base (0,2,..,14)
    const int jb = (pt & 7) * 2;    // j_loc base
    const int c0 = ch * 12;

    // per-pair constants [ii][jj]
    float Ci00[2][2], Ci01[2][2], Ci11[2][2], Cm01[2][2];
    float Cqd[2][2], Cqj[2][2], Cqi[2][2], Cc2[2][2];
    {
        const float* kb = kin + (size_t)b * NN * NN;
#pragma unroll
        for (int ii = 0; ii < 2; ++ii) {
            const int gi = ti * TT + ia + ii;
            const float m00 = srowV[ia + ii];
            float2 k2 = *(const float2*)(kb + (size_t)gi * NN + tj * TT + jb);
#pragma unroll
            for (int jj = 0; jj < 2; ++jj) {
                const float m11 = srowV[16 + jb + jj];
                const float m01 = (jj == 0) ? k2.x : k2.y;
                const float det = __builtin_fmaf(-m01, m01, m00 * m11);
                const float s   = __builtin_amdgcn_sqrtf(fmaxf(det, 1e-8f));
                const float tt  = fmaxf(__builtin_amdgcn_sqrtf(m00 + m11 + 2.0f * s), 1e-8f);
                const float rt  = __builtin_amdgcn_rcpf(tt);
                const float s00 = (m00 + s) * rt;
                const float s01 = m01 * rt;
                const float s11 = (m11 + s) * rt;
                const float dS  = fmaxf(__builtin_fmaf(-s01, s01, s00 * s11), 1e-8f);
                const float rdS = __builtin_amdgcn_rcpf(dS);
                Ci00[ii][jj] = s11 * rdS;
                Ci01[ii][jj] = -s01 * rdS;
                Ci11[ii][jj] = s00 * rdS;
                Cm01[ii][jj] = m01;
                Cqd[ii][jj]  = -INV_SQRT_2PI * s01 * s01 * s01 * rdS;
                Cqj[ii][jj]  =  INV_SQRT_2PI * s00 * s00 * s11 * rdS;
                Cqi[ii][jj]  =  INV_SQRT_2PI * s00 * s11 * s11 * rdS;
                Cc2[ii][jj]  = 2.0f * INV_SQRT_2PI * INV_SQRT_2PI * s01 * s01;
            }
        }
    }

    v2f acc[2][2] = {{v2s(0.0f), v2s(0.0f)}, {v2s(0.0f), v2s(0.0f)}};

    // packed elem: 2 c's per call; fully packed incl. clamps.
    auto elem2 = [&](int ii, int jj, v2f mi, v2f mj, v2f Ei, v2f Ej) {
        v2f u1 = V2FMA(v2s(Ci01[ii][jj]), mj, v2s(Ci00[ii][jj]) * mi);
        v2f u2 = V2FMA(v2s(Ci11[ii][jj]), mj, v2s(Ci01[ii][jj]) * mi);
        v2f uc1 = v2_clamp3(u1);
        v2f uc2 = v2_clamp3(u2);
        v2f s1 = uc1 * uc1;
        v2f s2 = uc2 * uc2;
        v2f P1 = V2FMA(V2FMA(V2FMA(v2s(PA3), s1, v2s(PA2)), s1, v2s(PA1)), s1, v2s(PA0));
        v2f P2 = V2FMA(V2FMA(V2FMA(v2s(PA3), s2, v2s(PA2)), s2, v2s(PA1)), s2, v2s(PA0));
        v2f Phi1 = V2FMA(uc1, P1, v2s(0.5f));
        v2f Phi2 = V2FMA(uc2, P2, v2s(0.5f));
        v2f e1 = V2FMA(V2FMA(V2FMA(V2FMA(v2s(PB4), s1, v2s(PB3)), s1, v2s(PB2)),
                             s1, v2s(PB1)), s1, v2s(PB0));
        v2f e2 = V2FMA(V2FMA(V2FMA(V2FMA(v2s(PB4), s2, v2s(PB3)), s2, v2s(PB2)),
                             s2, v2s(PB1)), s2, v2s(PB0));
        v2f a  = V2FMA(mi, mj, v2s(Cm01[ii][jj]));
        v2f bb = V2FMA(v2s(Cqd[ii][jj]), mi, v2s(Cqj[ii][jj]) * mj);
        v2f cc = V2FMA(v2s(Cqi[ii][jj]), mi, v2s(Cqd[ii][jj]) * mj);
        v2f ta = V2FMA(a,  Phi1, bb * e1);
        v2f tb = V2FMA(cc, Phi1, v2s(Cc2[ii][jj]) * e1);
        v2f A  = acc[ii][jj];
        A = V2FMA(Phi2, ta, A);
        A = V2FMA(e2,   tb, A);
        A = V2FMA(-Ei,  Ej, A);
        acc[ii][jj] = A;
    };

#pragma unroll
    for (int q = 0; q < 3; ++q) {
        const int co = c0 + q * 4;
        float4 mi4[2], Ei4[2], mj4[2], Ej4[2];
#pragma unroll
        for (int r = 0; r < 2; ++r) {
            mi4[r] = *(const float4*)(smi + (ia + r) * RSTR + co);
            Ei4[r] = *(const float4*)(sEi + (ia + r) * RSTR + co);
            mj4[r] = *(const float4*)(smj + (jb + r) * RSTR + co);
            Ej4[r] = *(const float4*)(sEj + (jb + r) * RSTR + co);
        }
#pragma unroll
        for (int ii = 0; ii < 2; ++ii) {
#pragma unroll
            for (int jj = 0; jj < 2; ++jj) {
                v2f miL = {mi4[ii].x, mi4[ii].y}, miH = {mi4[ii].z, mi4[ii].w};
                v2f mjL = {mj4[jj].x, mj4[jj].y}, mjH = {mj4[jj].z, mj4[jj].w};
                v2f EiL = {Ei4[ii].x, Ei4[ii].y}, EiH = {Ei4[ii].z, Ei4[ii].w};
                v2f EjL = {Ej4[jj].x, Ej4[jj].y}, EjH = {Ej4[jj].z, Ej4[jj].w};
                elem2(ii, jj, miL, mjL, EiL, EjL);
                elem2(ii, jj, miH, mjH, EiH, EjH);
            }
        }
    }

#pragma unroll
    for (int ii = 0; ii < 2; ++ii)
#pragma unroll
        for (int jj = 0; jj < 2; ++jj)
            red[ch * 256 + (ia + ii) * 16 + (jb + jj)] =
                acc[ii][jj].x + acc[ii][jj].y;
    __syncthreads();

    if (tid < 256) {
        float sum = 0.0f;
#pragma unroll
        for (int k = 0; k < 8; ++k) sum += red[k * 256 + tid];
        const int i = ti * TT + (tid >> 4);
        const int j = tj * TT + (tid & 15);
        if (i < j) {
            float v = sum * (1.0f / 96.0f);
            out[COV_OFF + ((size_t)(b * NN + i)) * NN + j] = v;
            out[COV_OFF + ((size_t)(b * NN + j)) * NN + i] = v;
        }
    }
}

extern "C" void kernel_launch(void* const* d_in, const int* in_sizes, int n_in,
                              void* d_out, int out_size, void* d_ws, size_t ws_size,
                              hipStream_t stream) {
    const float* xin    = (const float*)d_in[0];
    const float* meanin = (const float*)d_in[1];
    const float* kin    = (const float*)d_in[2];
    float* out = (float*)d_out;

    relu_cov_fused<<<BSZ * NTILES, 512, 0, stream>>>(xin, meanin, kin, out);
}

// Round 16
// 73.624 us; speedup vs baseline: 1.0181x; 1.0089x over previous
//
#include <hip/hip_runtime.h>
#include <math.h>

#define BSZ 4
#define NN  256
#define CC  96
#define TT  16                 // tile side
#define NTILES 136             // 16*17/2 triangular tiles per batch
#define RSTR 100               // LDS row stride (floats): 16B-aligned, 2-way banks free
#define ARR  (TT * RSTR)       // 1600 floats per array

#define XIN_OFF  0
#define EH_OFF   2048          // BSZ*NN*2
#define COV_OFF  100352        // 2048 + BSZ*NN*CC

#define INV_SQRT_2PI 0.3989422804014327f
#define EXP2C       -0.7213475204444817f   // -0.5*log2(e)
// Output-accuracy path (Eh output, dvals): A&S 7.1.25, Phi abs err ~1.3e-5.
#define PHI_P   0.33267253f
#define PHI_C1  0.1740121f
#define PHI_C2 -0.0479399f
#define PHI_C3  0.3739278f
// Poly path (pair loop + LDS-Eh): clamped odd cubic Phi fit (R11).
#define PA0  0.39712f
#define PA1 -0.060411f
#define PA2  0.0061591f
#define PA3 -0.00025640f
// Poly pdf: quartic fit of exp(-s/2), s=u^2 in [0,9] (R13).
#define PB0  0.99521f
#define PB1 -0.471073f
#define PB2  0.0955511f
#define PB3 -0.00930823f
#define PB4  0.000351287f

typedef float v2f __attribute__((ext_vector_type(2)));

__device__ __forceinline__ v2f v2s(float s) { v2f r; r.x = s; r.y = s; return r; }

#if __has_builtin(__builtin_elementwise_fma)
#define V2FMA(a, b, c) __builtin_elementwise_fma((v2f)(a), (v2f)(b), (v2f)(c))
#else
#define V2FMA(a, b, c) ((a) * (b) + (c))
#endif

#if __has_builtin(__builtin_elementwise_min) && __has_builtin(__builtin_elementwise_max)
__device__ __forceinline__ v2f v2_clamp3(v2f u) {
    return __builtin_elementwise_max(__builtin_elementwise_min(u, v2s(3.0f)), v2s(-3.0f));
}
#else
__device__ __forceinline__ v2f v2_clamp3(v2f u) {
    v2f r;
    r.x = fminf(fmaxf(u.x, -3.0f), 3.0f);
    r.y = fminf(fmaxf(u.y, -3.0f), 3.0f);
    return r;
}
#endif

__device__ __forceinline__ float phi_from_exp_s(float u, float e) {
    float t  = __builtin_amdgcn_rcpf(__builtin_fmaf(PHI_P, fabsf(u), 1.0f));
    float hp = __builtin_fmaf(__builtin_fmaf(PHI_C3, t, PHI_C2), t, PHI_C1) * t * e;
    return 0.5f + __builtin_copysignf(0.5f - hp, u);
}

__device__ __forceinline__ int tri_offset(int k) {   // tiles before row k
    return k * TT - (k * (k - 1)) / 2;
}
__device__ __forceinline__ void tri_decode(int t, int& ti, int& tj) {
    float disc = 1089.0f - 8.0f * (float)t;          // (2T+1)^2 - 8t, T=16
    ti = (int)((33.0f - __builtin_amdgcn_sqrtf(disc)) * 0.5f);
    while (tri_offset(ti + 1) <= t) ++ti;            // float-precision fixup
    while (tri_offset(ti) > t) --ti;
    tj = ti + (t - tri_offset(ti));
}

// Single fused kernel (R13 structure). Phase 2 (LDS Eh, feeds only the
// Ei*Ej covar term) now uses the packed trans-free polynomial path; the
// Eh OUTPUT and dvals keep the accurate A&S path (Phase 2b, diag blocks).
__global__ __launch_bounds__(512) void relu_cov_fused(
    const float* __restrict__ xin, const float* __restrict__ meanin,
    const float* __restrict__ kin, float* __restrict__ out)
{
    const int blk = blockIdx.x;     // b*NTILES + t
    const int b   = blk / NTILES;
    const int t   = blk - b * NTILES;
    const int tid = threadIdx.x;

    int ti, tj;
    tri_decode(t, ti, tj);
    const bool diag = (ti == tj);

    __shared__ __align__(16) float lds[4 * ARR];   // [smi | sEi | smj | sEj]
    __shared__ float red[8 * 256];                 // [chunk][pair]
    __shared__ float srowS[32], srowR[32], srowV[32];
    float* const smi = lds;
    float* const sEi = lds + ARR;
    float* const smj = lds + 2 * ARR;
    float* const sEj = lds + 3 * ARR;

    // --- Phase 1: row consts + stage meanin ---
    if (tid < 32) {
        int row = (tid < 16) ? (ti * TT + tid) : (tj * TT + (tid - 16));
        float kd  = kin[((size_t)(b * NN + row)) * NN + row] + 1e-6f;
        float var = fmaxf(kd, 1e-8f);
        float st  = __builtin_amdgcn_sqrtf(var);
        srowV[tid] = var;
        srowS[tid] = st;
        srowR[tid] = __builtin_amdgcn_rcpf(st);
    }
#pragma unroll
    for (int it = 0; it < 2; ++it) {
        int k = tid + it * 512;         // 2 arrays x 16 rows x 24 float4 = 768
        if (k < 768) {
            int arr = k / 384;          // 0 = i-rows, 1 = j-rows
            int rem = k - arr * 384;
            int r   = rem / 24;
            int q   = rem - r * 24;
            int row = ((arr == 0) ? ti : tj) * TT + r;
            float4 v = *((const float4*)(meanin + ((size_t)(b * NN + row)) * CC) + q);
            *(float4*)(lds + arr * 2 * ARR + r * RSTR + q * 4) = v;
        }
    }
    __syncthreads();

    // --- Phase 2: LDS Eh for 32 rows — packed poly path (zero trans).
    //     2 arrays x 16 rows x 48 c-pairs = 1536 pairs, 3/thread. ---
#pragma unroll
    for (int it = 0; it < 3; ++it) {
        int k   = tid + it * 512;
        int arr = k / 768;
        int rem = k - arr * 768;
        int r   = rem / 48;
        int cp  = rem - r * 48;
        int c   = cp * 2;
        float st = srowS[arr * 16 + r];
        float rs = srowR[arr * 16 + r];
        v2f m  = *(const v2f*)(lds + arr * 2 * ARR + r * RSTR + c);
        v2f z  = m * v2s(rs);
        v2f uc = v2_clamp3(z);
        v2f s  = uc * uc;
        v2f P  = V2FMA(V2FMA(V2FMA(v2s(PA3), s, v2s(PA2)), s, v2s(PA1)), s, v2s(PA0));
        v2f Ph = V2FMA(uc, P, v2s(0.5f));
        v2f e  = V2FMA(V2FMA(V2FMA(V2FMA(v2s(PB4), s, v2s(PB3)), s, v2s(PB2)),
                             s, v2s(PB1)), s, v2s(PB0));
        v2f Eh = V2FMA(m, Ph, v2s(st * INV_SQRT_2PI) * e);
        *(v2f*)(lds + (arr * 2 + 1) * ARR + r * RSTR + c) = Eh;
    }
    __syncthreads();

    // --- Phase 2b: diagonal-tile global outputs (accurate A&S path) ---
    if (diag) {
#pragma unroll
        for (int it = 0; it < 3; ++it) {         // Eh output: 16 x 96, recomputed
            int k = tid + it * 512;
            int r = k / 96, c = k - r * 96;
            float m  = smi[r * RSTR + c];
            float st = srowS[r], rs = srowR[r];
            float z  = m * rs;
            float e  = __builtin_amdgcn_exp2f(z * z * EXP2C);
            float Ph = phi_from_exp_s(z, e);
            float Eh = __builtin_fmaf(m, Ph, st * (INV_SQRT_2PI * e));
            out[EH_OFF + ((size_t)(b * NN + ti * TT + r)) * CC + c] = Eh;
        }
        if (tid < 32) {                          // xin copy: 16 rows x 2
            int r = tid >> 1, d = tid & 1;
            size_t o = ((size_t)(b * NN + ti * TT + r)) * 2 + d;
            out[XIN_OFF + o] = xin[o];
        }
        {                                        // dvals: tid = r*32 + s, 3 c each
            int r = tid >> 5, s = tid & 31;
            float st = srowS[r], var = srowV[r], rs = srowR[r];
            float dsum = 0.0f;
#pragma unroll
            for (int dc = 0; dc < 3; ++dc) {
                int c = s * 3 + dc;
                float m  = smi[r * RSTR + c];
                float z  = m * rs;
                float e  = __builtin_amdgcn_exp2f(z * z * EXP2C);
                float Ph = phi_from_exp_s(z, e);
                float ph = INV_SQRT_2PI * e;
                float Eh = __builtin_fmaf(m, Ph, st * ph);   // accurate, free
                float dt = __builtin_fmaf(__builtin_fmaf(m, m, var), Ph,
                           __builtin_fmaf(m * st, ph, -Eh * Eh));
                dsum += dt;
            }
            dsum += __shfl_down(dsum, 16, 32);
            dsum += __shfl_down(dsum,  8, 32);
            dsum += __shfl_down(dsum,  4, 32);
            dsum += __shfl_down(dsum,  2, 32);
            dsum += __shfl_down(dsum,  1, 32);
            if (s == 0) {
                float dval = fmaxf(dsum * (1.0f / 96.0f), 1e-6f);
                int row = ti * TT + r;
                out[COV_OFF + ((size_t)(b * NN + row)) * NN + row] = dval + 1e-6f;
            }
        }
    }

    // --- Phase 3: pair loop, 2x2 pairs per thread, packed, trans-free ---
    const int pt = tid & 63;        // pair-thread
    const int ch = tid >> 6;        // c-chunk 0..7 (12 c each)
    const int ia = (pt >> 3) * 2;   // i_loc base (0,2,..,14)
    const int jb = (pt & 7) * 2;    // j_loc base
    const int c0 = ch * 12;

    // per-pair constants [ii][jj]
    float Ci00[2][2], Ci01[2][2], Ci11[2][2], Cm01[2][2];
    float Cqd[2][2], Cqj[2][2], Cqi[2][2], Cc2[2][2];
    {
        const float* kb = kin + (size_t)b * NN * NN;
#pragma unroll
        for (int ii = 0; ii < 2; ++ii) {
            const int gi = ti * TT + ia + ii;
            const float m00 = srowV[ia + ii];
            float2 k2 = *(const float2*)(kb + (size_t)gi * NN + tj * TT + jb);
#pragma unroll
            for (int jj = 0; jj < 2; ++jj) {
                const float m11 = srowV[16 + jb + jj];
                const float m01 = (jj == 0) ? k2.x : k2.y;
                const float det = __builtin_fmaf(-m01, m01, m00 * m11);
                const float s   = __builtin_amdgcn_sqrtf(fmaxf(det, 1e-8f));
                const float tt  = fmaxf(__builtin_amdgcn_sqrtf(m00 + m11 + 2.0f * s), 1e-8f);
                const float rt  = __builtin_amdgcn_rcpf(tt);
                const float s00 = (m00 + s) * rt;
                const float s01 = m01 * rt;
                const float s11 = (m11 + s) * rt;
                const float dS  = fmaxf(__builtin_fmaf(-s01, s01, s00 * s11), 1e-8f);
                const float rdS = __builtin_amdgcn_rcpf(dS);
                Ci00[ii][jj] = s11 * rdS;
                Ci01[ii][jj] = -s01 * rdS;
                Ci11[ii][jj] = s00 * rdS;
                Cm01[ii][jj] = m01;
                Cqd[ii][jj]  = -INV_SQRT_2PI * s01 * s01 * s01 * rdS;
                Cqj[ii][jj]  =  INV_SQRT_2PI * s00 * s00 * s11 * rdS;
                Cqi[ii][jj]  =  INV_SQRT_2PI * s00 * s11 * s11 * rdS;
                Cc2[ii][jj]  = 2.0f * INV_SQRT_2PI * INV_SQRT_2PI * s01 * s01;
            }
        }
    }

    v2f acc[2][2] = {{v2s(0.0f), v2s(0.0f)}, {v2s(0.0f), v2s(0.0f)}};

    auto elem2 = [&](int ii, int jj, v2f mi, v2f mj, v2f Ei, v2f Ej) {
        v2f u1 = V2FMA(v2s(Ci01[ii][jj]), mj, v2s(Ci00[ii][jj]) * mi);
        v2f u2 = V2FMA(v2s(Ci11[ii][jj]), mj, v2s(Ci01[ii][jj]) * mi);
        v2f uc1 = v2_clamp3(u1);
        v2f uc2 = v2_clamp3(u2);
        v2f s1 = uc1 * uc1;
        v2f s2 = uc2 * uc2;
        v2f P1 = V2FMA(V2FMA(V2FMA(v2s(PA3), s1, v2s(PA2)), s1, v2s(PA1)), s1, v2s(PA0));
        v2f P2 = V2FMA(V2FMA(V2FMA(v2s(PA3), s2, v2s(PA2)), s2, v2s(PA1)), s2, v2s(PA0));
        v2f Phi1 = V2FMA(uc1, P1, v2s(0.5f));
        v2f Phi2 = V2FMA(uc2, P2, v2s(0.5f));
        v2f e1 = V2FMA(V2FMA(V2FMA(V2FMA(v2s(PB4), s1, v2s(PB3)), s1, v2s(PB2)),
                             s1, v2s(PB1)), s1, v2s(PB0));
        v2f e2 = V2FMA(V2FMA(V2FMA(V2FMA(v2s(PB4), s2, v2s(PB3)), s2, v2s(PB2)),
                             s2, v2s(PB1)), s2, v2s(PB0));
        v2f a  = V2FMA(mi, mj, v2s(Cm01[ii][jj]));
        v2f bb = V2FMA(v2s(Cqd[ii][jj]), mi, v2s(Cqj[ii][jj]) * mj);
        v2f cc = V2FMA(v2s(Cqi[ii][jj]), mi, v2s(Cqd[ii][jj]) * mj);
        v2f ta = V2FMA(a,  Phi1, bb * e1);
        v2f tb = V2FMA(cc, Phi1, v2s(Cc2[ii][jj]) * e1);
        v2f A  = acc[ii][jj];
        A = V2FMA(Phi2, ta, A);
        A = V2FMA(e2,   tb, A);
        A = V2FMA(-Ei,  Ej, A);
        acc[ii][jj] = A;
    };

#pragma unroll
    for (int q = 0; q < 3; ++q) {
        const int co = c0 + q * 4;
        float4 mi4[2], Ei4[2], mj4[2], Ej4[2];
#pragma unroll
        for (int r = 0; r < 2; ++r) {
            mi4[r] = *(const float4*)(smi + (ia + r) * RSTR + co);
            Ei4[r] = *(const float4*)(sEi + (ia + r) * RSTR + co);
            mj4[r] = *(const float4*)(smj + (jb + r) * RSTR + co);
            Ej4[r] = *(const float4*)(sEj + (jb + r) * RSTR + co);
        }
#pragma unroll
        for (int ii = 0; ii < 2; ++ii) {
#pragma unroll
            for (int jj = 0; jj < 2; ++jj) {
                v2f miL = {mi4[ii].x, mi4[ii].y}, miH = {mi4[ii].z, mi4[ii].w};
                v2f mjL = {mj4[jj].x, mj4[jj].y}, mjH = {mj4[jj].z, mj4[jj].w};
                v2f EiL = {Ei4[ii].x, Ei4[ii].y}, EiH = {Ei4[ii].z, Ei4[ii].w};
                v2f EjL = {Ej4[jj].x, Ej4[jj].y}, EjH = {Ej4[jj].z, Ej4[jj].w};
                elem2(ii, jj, miL, mjL, EiL, EjL);
                elem2(ii, jj, miH, mjH, EiH, EjH);
            }
        }
    }

#pragma unroll
    for (int ii = 0; ii < 2; ++ii)
#pragma unroll
        for (int jj = 0; jj < 2; ++jj)
            red[ch * 256 + (ia + ii) * 16 + (jb + jj)] =
                acc[ii][jj].x + acc[ii][jj].y;
    __syncthreads();

    if (tid < 256) {
        float sum = 0.0f;
#pragma unroll
        for (int k = 0; k < 8; ++k) sum += red[k * 256 + tid];
        const int i = ti * TT + (tid >> 4);
        const int j = tj * TT + (tid & 15);
        if (i < j) {
            float v = sum * (1.0f / 96.0f);
            out[COV_OFF + ((size_t)(b * NN + i)) * NN + j] = v;
            out[COV_OFF + ((size_t)(b * NN + j)) * NN + i] = v;
        }
    }
}

extern "C" void kernel_launch(void* const* d_in, const int* in_sizes, int n_in,
                              void* d_out, int out_size, void* d_ws, size_t ws_size,
                              hipStream_t stream) {
    const float* xin    = (const float*)d_in[0];
    const float* meanin = (const float*)d_in[1];
    const float* kin    = (const float*)d_in[2];
    float* out = (float*)d_out;

    relu_cov_fused<<<BSZ * NTILES, 512, 0, stream>>>(xin, meanin, kin, out);
}